// Round 11
// baseline (723.525 us; speedup 1.0000x reference)
//
#include <hip/hip_runtime.h>
#include <hip/hip_bf16.h>

#define NNODES 50000
#define NEDGES 400000
#define NGRAPH 16

typedef __attribute__((ext_vector_type(4))) float floatx4;
typedef __attribute__((ext_vector_type(8))) short short8;

typedef __attribute__((address_space(3))) unsigned int lds_uint;
typedef __attribute__((address_space(1))) const unsigned int gbl_uint;

__device__ __forceinline__ void load16_to_lds(const void* g, void* l) {
    __builtin_amdgcn_global_load_lds((gbl_uint*)g, (lds_uint*)l, 16, 0, 0);
}

// ---------------------------------------------------------------------------
__global__ __launch_bounds__(64) void zero_out_k(float* out, int n) {
    int i = blockIdx.x * 64 + threadIdx.x;
    if (i < n) out[i] = 0.0f;
}

// init: zero counters/accumulators + pack x rows into float4
__global__ __launch_bounds__(256) void init_k(int* deg_cnt, int* cursor,
                                              float* gsum, int* gcnt,
                                              const float* __restrict__ x,
                                              float4* __restrict__ xp, int n) {
    int i = blockIdx.x * 256 + threadIdx.x;
    if (i < n) {
        deg_cnt[i] = 0; cursor[i] = 0;
        xp[i] = make_float4(x[i * 3 + 0], x[i * 3 + 1], x[i * 3 + 2], 0.0f);
    }
    if (i < NGRAPH * 512) gsum[i] = 0.0f;
    if (i < NGRAPH) gcnt[i] = 0;
}

__global__ __launch_bounds__(256) void deg_k(const int* __restrict__ col,
                                             int* __restrict__ deg_cnt, int e) {
    int i = blockIdx.x * 256 + threadIdx.x;
    if (i < e) atomicAdd(&deg_cnt[col[i]], 1);
}

// single-block exclusive scan of cnt -> offs[0..n] (+ fused dis = rsqrt(cnt+1))
__global__ __launch_bounds__(1024) void scan_k(const int* __restrict__ cnt,
                                               int* __restrict__ offs,
                                               float* __restrict__ dis, int n) {
    __shared__ int sbuf[1024];
    int t = threadIdx.x;
    int chunk = (n + 1023) / 1024;
    int beg = t * chunk;
    int end = min(beg + chunk, n);
    int s = 0;
    for (int i = beg; i < end; ++i) s += cnt[i];
    sbuf[t] = s;
    __syncthreads();
    for (int off = 1; off < 1024; off <<= 1) {
        int v = (t >= off) ? sbuf[t - off] : 0;
        __syncthreads();
        sbuf[t] += v;
        __syncthreads();
    }
    int run = sbuf[t] - s;
    for (int i = beg; i < end; ++i) {
        offs[i] = run;
        int c = cnt[i];
        dis[i] = rsqrtf((float)(c + 1));
        run += c;
    }
    if (t == 1023) offs[n] = sbuf[1023];
}

__global__ __launch_bounds__(256) void scatter_k(const int* __restrict__ row,
                                                 const int* __restrict__ col,
                                                 const int* __restrict__ offs,
                                                 int* __restrict__ cursor,
                                                 int* __restrict__ ssrc,
                                                 float* __restrict__ sw,
                                                 const float* __restrict__ dis, int e) {
    int i = blockIdx.x * 256 + threadIdx.x;
    if (i >= e) return;
    int d = col[i];
    int p = offs[d] + atomicAdd(&cursor[d], 1);
    int s = row[i];
    ssrc[p] = s;
    sw[p]   = dis[s];
}

// FUSED layer 1: h1 = relu((A_norm x) @ W1 + b1) -> bf16
// one WAVE per node: lanes gather edges in parallel (12B each), 6-step
// shuffle reduction of the 3-float aggregate, then all lanes compute the
// 512-wide GEMM epilogue (8 feats/lane, short8 store).
__global__ __launch_bounds__(256) void layer1_k(const float4* __restrict__ xp,
                                                const int* __restrict__ offs,
                                                const int* __restrict__ ssrc,
                                                const float* __restrict__ sw,
                                                const float* __restrict__ dis,
                                                const float* __restrict__ W1,
                                                const float* __restrict__ b1,
                                                __hip_bfloat16* __restrict__ h1, int n) {
    int wave = threadIdx.x >> 6;
    int lane = threadIdx.x & 63;
    int d = blockIdx.x * 4 + wave;
    if (d >= n) return;
    float dd = dis[d];
    int beg = offs[d], end = offs[d + 1];
    float a0 = 0.f, a1 = 0.f, a2 = 0.f;
    for (int e = beg + lane; e < end; e += 64) {
        int s = ssrc[e];
        float w = sw[e];
        float4 q = xp[s];
        a0 += w * q.x; a1 += w * q.y; a2 += w * q.z;
    }
#pragma unroll
    for (int off = 32; off > 0; off >>= 1) {
        a0 += __shfl_down(a0, off);
        a1 += __shfl_down(a1, off);
        a2 += __shfl_down(a2, off);
    }
    a0 = __shfl(a0, 0); a1 = __shfl(a1, 0); a2 = __shfl(a2, 0);
    float4 xd = xp[d];
    a0 = dd * (a0 + dd * xd.x);
    a1 = dd * (a1 + dd * xd.y);
    a2 = dd * (a2 + dd * xd.z);
    int f0 = lane * 8;
    short8 ov;
#pragma unroll
    for (int j = 0; j < 8; ++j) {
        int f = f0 + j;
        float v = b1[f] + a0 * W1[f] + a1 * W1[512 + f] + a2 * W1[1024 + f];
        __hip_bfloat16 h = __float2bfloat16(fmaxf(v, 0.0f));
        ov[j] = *(short*)&h;
    }
    *(short8*)&h1[(size_t)d * 512 + f0] = ov;
}

__device__ inline float bs2f(short v) {
    return __uint_as_float(((unsigned int)(unsigned short)v) << 16);
}

// aggregation F=512: one WAVE per node, 16B loads, edge loop unrolled x8
// (8 outstanding 1KB gathers — queue-depth probe vs the 4-deep R8 version)
__global__ __launch_bounds__(256) void agg512w_k(const __hip_bfloat16* __restrict__ in,
                                                 __hip_bfloat16* __restrict__ out,
                                                 const int* __restrict__ offs,
                                                 const int* __restrict__ ssrc,
                                                 const float* __restrict__ sw,
                                                 const float* __restrict__ dis,
                                                 const float* __restrict__ bias,
                                                 int relu, int n) {
    int wave = threadIdx.x >> 6;
    int lane = threadIdx.x & 63;
    int d = blockIdx.x * 4 + wave;
    if (d >= n) return;
    float dd = dis[d];
    short8 p = *(const short8*)&in[(size_t)d * 512 + lane * 8];
    float acc[8];
#pragma unroll
    for (int j = 0; j < 8; ++j) acc[j] = dd * bs2f(p[j]);

    int beg = offs[d], end = offs[d + 1];
    int e = beg;
    for (; e + 7 < end; e += 8) {
        short8 q[8];
        float w[8];
#pragma unroll
        for (int u = 0; u < 8; ++u) {
            int s = ssrc[e + u];
            w[u] = sw[e + u];
            q[u] = *(const short8*)&in[(size_t)s * 512 + lane * 8];
        }
#pragma unroll
        for (int u = 0; u < 8; ++u)
#pragma unroll
            for (int j = 0; j < 8; ++j) acc[j] += w[u] * bs2f(q[u][j]);
    }
    for (; e + 3 < end; e += 4) {
        short8 q[4];
        float w[4];
#pragma unroll
        for (int u = 0; u < 4; ++u) {
            int s = ssrc[e + u];
            w[u] = sw[e + u];
            q[u] = *(const short8*)&in[(size_t)s * 512 + lane * 8];
        }
#pragma unroll
        for (int u = 0; u < 4; ++u)
#pragma unroll
            for (int j = 0; j < 8; ++j) acc[j] += w[u] * bs2f(q[u][j]);
    }
    for (; e < end; ++e) {
        int s = ssrc[e];
        float w0 = sw[e];
        short8 q0 = *(const short8*)&in[(size_t)s * 512 + lane * 8];
#pragma unroll
        for (int j = 0; j < 8; ++j) acc[j] += w0 * bs2f(q0[j]);
    }

    short8 ov;
#pragma unroll
    for (int j = 0; j < 8; ++j) {
        float v = acc[j] * dd;
        if (bias) v += bias[lane * 8 + j];
        if (relu) v = fmaxf(v, 0.0f);
        __hip_bfloat16 h = __float2bfloat16(v);
        ov[j] = *(short*)&h;
    }
    *(short8*)&out[(size_t)d * 512 + lane * 8] = ov;
}

// merged transpose+convert for BOTH weight matrices, 1D-decoded:
// blocks [0,512): W2[512][1024] -> w2t[1024][512]
// blocks [512,1024): W3[1024][512] -> w3t[512][1024]
__global__ __launch_bounds__(256) void tcvt_k(const float* __restrict__ W2,
                                              __hip_bfloat16* __restrict__ w2t,
                                              const float* __restrict__ W3,
                                              __hip_bfloat16* __restrict__ w3t) {
    __shared__ float tile[32][33];
    int t = threadIdx.x;
    const float* W; __hip_bfloat16* Wt;
    int K, N, idx;
    if (blockIdx.x < 512) { W = W2; Wt = w2t; K = 512;  N = 1024; idx = blockIdx.x; }
    else                  { W = W3; Wt = w3t; K = 1024; N = 512;  idx = blockIdx.x - 512; }
    int nbn = N / 32;
    int bn = (idx % nbn) * 32;
    int bk = (idx / nbn) * 32;
    int c = t & 31, r0 = t >> 5;
#pragma unroll
    for (int j = 0; j < 4; ++j) {
        int r = r0 + j * 8;
        tile[r][c] = W[(size_t)(bk + r) * N + bn + c];
    }
    __syncthreads();
#pragma unroll
    for (int j = 0; j < 4; ++j) {
        int r = r0 + j * 8;
        Wt[(size_t)(bn + r) * K + bk + c] = __float2bfloat16(tile[c][r]);
    }
}

// bf16 MFMA GEMM (R8 config — best measured): C[M,N] = epi(A@Bt^T + bias)
// 128x128 tile, BK=32, 4 waves, fragment-major global_load_lds staging,
// double-buffered, 1 barrier/iter, XCD swizzle, 4 blocks/CU.
__global__ __launch_bounds__(256, 4) void mfma_gemm_k(const __hip_bfloat16* __restrict__ A,
                                                      const __hip_bfloat16* __restrict__ Bt,
                                                      const float* __restrict__ bias,
                                                      __hip_bfloat16* __restrict__ C,
                                                      int M, int N, int K, int relu,
                                                      int lnbx) {
    __shared__ short smem[17408];

    int tid  = threadIdx.x;
    int lane = tid & 63;
    int wave = tid >> 6;
    int wm = (wave >> 1) * 64;
    int wn = (wave & 1) * 64;
    int fr = lane & 15;
    int kg = lane >> 4;

    int b  = blockIdx.x;
    int r8 = b & 7;
    int j  = (b >> 3) & ((1 << lnbx) - 1);
    int g8 = b >> (3 + lnbx);
    int bm = (g8 * 8 + r8) * 128;
    int bn = j * 128;

    const __hip_bfloat16* gbase;
    if (wave < 2) gbase = A  + (size_t)(bm + wave * 64 + fr) * K;
    else          gbase = Bt + (size_t)(bn + (wave - 2) * 64 + fr) * K;
    gbase += kg * 8;
    size_t segstr = (size_t)16 * K;

    floatx4 acc[4][4] = {};

#pragma unroll
    for (int i = 0; i < 4; ++i)
        load16_to_lds(gbase + i * segstr, &smem[(wave * 4 + i) * 512]);
    gbase += 32;

    int cur = 0;
    for (int k0 = 0; k0 < K; k0 += 32) {
        __syncthreads();
        int nxt = cur ^ 8192;
        if (k0 + 32 < K) {
#pragma unroll
            for (int i = 0; i < 4; ++i)
                load16_to_lds(gbase + i * segstr, &smem[nxt + (wave * 4 + i) * 512]);
            gbase += 32;
        }

        short8 af[4], bf[4];
#pragma unroll
        for (int mi = 0; mi < 4; ++mi)
            af[mi] = *(short8*)&smem[cur + ((wm >> 4) + mi) * 512 + lane * 8];
#pragma unroll
        for (int ni = 0; ni < 4; ++ni)
            bf[ni] = *(short8*)&smem[cur + (8 + (wn >> 4) + ni) * 512 + lane * 8];
#pragma unroll
        for (int mi = 0; mi < 4; ++mi)
#pragma unroll
            for (int ni = 0; ni < 4; ++ni)
                acc[mi][ni] = __builtin_amdgcn_mfma_f32_16x16x32_bf16(
                    af[mi], bf[ni], acc[mi][ni], 0, 0, 0);
        cur = nxt;
    }
    __syncthreads();

    short* Cs = smem;
#pragma unroll
    for (int mi = 0; mi < 4; ++mi) {
#pragma unroll
        for (int ni = 0; ni < 4; ++ni) {
            int rl = wm + mi * 16 + (lane >> 4) * 4;
            int cl = wn + ni * 16 + (lane & 15);
            float bv = bias ? bias[bn + cl] : 0.0f;
#pragma unroll
            for (int r = 0; r < 4; ++r) {
                float v = acc[mi][ni][r] + bv;
                if (relu) v = fmaxf(v, 0.0f);
                __hip_bfloat16 h = __float2bfloat16(v);
                Cs[(rl + r) * 136 + cl] = *(short*)&h;
            }
        }
    }
    __syncthreads();
#pragma unroll
    for (int i = 0; i < 8; ++i) {
        int c  = tid + 256 * i;
        int rr = c >> 4;
        int cc = c & 15;
        int grow = bm + rr;
        if (grow < M)
            *(short8*)&C[(size_t)grow * N + bn + cc * 8] =
                *(short8*)&Cs[rr * 136 + cc * 8];
    }
}

// pooled sums (bf16 input, LDS fp32 accumulators) + fused per-graph counts
__global__ __launch_bounds__(256) void pool_k(const __hip_bfloat16* __restrict__ h,
                                              const int* __restrict__ batch,
                                              float* __restrict__ gsum,
                                              int* __restrict__ gcnt, int n) {
    __shared__ float ls[NGRAPH * 512];
    __shared__ int lcnt[NGRAPH];
    int t = threadIdx.x;
    for (int i = t; i < NGRAPH * 512; i += 256) ls[i] = 0.0f;
    if (t < NGRAPH) lcnt[t] = 0;
    __syncthreads();
    for (int d = blockIdx.x; d < n; d += gridDim.x) {
        int g = batch[d];
        if (t == 0) atomicAdd(&lcnt[g], 1);
        unsigned int q = *(const unsigned int*)&h[(size_t)d * 512 + 2 * t];
        ls[g * 512 + 2 * t]     += __uint_as_float((q & 0xffffu) << 16);
        ls[g * 512 + 2 * t + 1] += __uint_as_float((q >> 16) << 16);
    }
    __syncthreads();
    for (int i = t; i < NGRAPH * 512; i += 256) atomicAdd(&gsum[i], ls[i]);
    if (t < NGRAPH) atomicAdd(&gcnt[t], lcnt[t]);
}

// head MLP (fp32)
__global__ __launch_bounds__(128) void fc_k(const float* __restrict__ gsum,
                                            const int* __restrict__ gcnt,
                                            const float* __restrict__ fcw1,
                                            const float* __restrict__ fcb1,
                                            const float* __restrict__ fcw2,
                                            const float* __restrict__ fcb2,
                                            float* __restrict__ out) {
    int g = blockIdx.x;
    int t = threadIdx.x;  // 128
    __shared__ float pooled[512];
    __shared__ float red[128];
    float inv = 1.0f / fmaxf((float)gcnt[g], 1.0f);
    for (int i = t; i < 512; i += 128) pooled[i] = gsum[g * 512 + i] * inv;
    __syncthreads();
    float s = fcb1[t];
    for (int k = 0; k < 512; ++k) s += pooled[k] * fcw1[k * 128 + t];
    s = fmaxf(s, 0.0f);
    red[t] = s * fcw2[t];
    __syncthreads();
    for (int off = 64; off > 0; off >>= 1) {
        if (t < off) red[t] += red[t + off];
        __syncthreads();
    }
    if (t == 0) out[g] = red[0] + fcb2[0];
}

extern "C" void kernel_launch(void* const* d_in, const int* in_sizes, int n_in,
                              void* d_out, int out_size, void* d_ws, size_t ws_size,
                              hipStream_t stream) {
    const float* x    = (const float*)d_in[0];
    const int*   ei   = (const int*)d_in[1];   // [2, E]
    const int*   batch= (const int*)d_in[2];
    const float* W1   = (const float*)d_in[3];
    const float* b1   = (const float*)d_in[4];
    const float* W2   = (const float*)d_in[5];
    const float* b2   = (const float*)d_in[6];
    const float* W3   = (const float*)d_in[7];
    const float* b3   = (const float*)d_in[8];
    const float* fcw1 = (const float*)d_in[9];
    const float* fcb1 = (const float*)d_in[10];
    const float* fcw2 = (const float*)d_in[11];
    const float* fcb2 = (const float*)d_in[12];
    float* out = (float*)d_out;

    const int N = in_sizes[0] / 3;      // 50000
    const int E = in_sizes[1] / 2;      // 400000
    const int Mpad = (N + 127) & ~127;  // GEMM A reads unguarded to Mpad
    const int* row = ei;
    const int* col = ei + E;

    // ---- workspace layout ----
    size_t used = 0;
    auto need = [&](size_t bytes) {
        size_t off = used;
        used += (bytes + 255) & ~(size_t)255;
        return off;
    };
    size_t o_deg  = need((size_t)N * 4);
    size_t o_cur  = need((size_t)N * 4);
    size_t o_dis  = need((size_t)N * 4);
    size_t o_offs = need((size_t)(N + 1) * 4);
    size_t o_ssrc = need((size_t)E * 4);
    size_t o_sw   = need((size_t)E * 4);
    size_t o_xp   = need((size_t)N * 16);            // packed x float4
    size_t o_gsum = need((size_t)NGRAPH * 512 * 4);
    size_t o_gcnt = need((size_t)NGRAPH * 4);
    size_t o_w2t  = need((size_t)512 * 1024 * 2);    // W2^T bf16
    size_t o_w3t  = need((size_t)1024 * 512 * 2);    // W3^T bf16
    size_t o_bufX = need((size_t)Mpad * 512 * 2);    // h1 -> g3   (bf16)
    size_t o_bufY = need((size_t)Mpad * 512 * 2);    // agg1 -> h3 (bf16)
    size_t o_bufZ = need((size_t)Mpad * 1024 * 2);   // h2         (bf16)

    if (used > ws_size) {
        hipLaunchKernelGGL(zero_out_k, dim3((out_size + 63) / 64), dim3(64), 0, stream,
                           out, out_size);
        return;
    }

    char* base = (char*)d_ws;
    int*    deg_cnt = (int*)   (base + o_deg);
    int*    cursor  = (int*)   (base + o_cur);
    float*  dis     = (float*) (base + o_dis);
    int*    offs    = (int*)   (base + o_offs);
    int*    ssrc    = (int*)   (base + o_ssrc);
    float*  sw      = (float*) (base + o_sw);
    float4* xp      = (float4*)(base + o_xp);
    float*  gsum    = (float*) (base + o_gsum);
    int*    gcnt    = (int*)   (base + o_gcnt);
    __hip_bfloat16* w2t  = (__hip_bfloat16*)(base + o_w2t);
    __hip_bfloat16* w3t  = (__hip_bfloat16*)(base + o_w3t);
    __hip_bfloat16* bufX = (__hip_bfloat16*)(base + o_bufX);
    __hip_bfloat16* bufY = (__hip_bfloat16*)(base + o_bufY);
    __hip_bfloat16* bufZ = (__hip_bfloat16*)(base + o_bufZ);
    (void)n_in;

    int gN = (N + 255) / 256;
    int gE = (E + 255) / 256;
    int gW = (N + 3) / 4;                         // wave-per-node grids
    int nby8 = (((N + 127) / 128 + 7) / 8) * 8;   // 128-row tiles, padded to x8

    // CSR build (+x packing, +dis fused into scan)
    hipLaunchKernelGGL(init_k, dim3(gN), dim3(256), 0, stream, deg_cnt, cursor, gsum, gcnt, x, xp, N);
    hipLaunchKernelGGL(deg_k, dim3(gE), dim3(256), 0, stream, col, deg_cnt, E);
    hipLaunchKernelGGL(scan_k, dim3(1), dim3(1024), 0, stream, deg_cnt, offs, dis, N);
    hipLaunchKernelGGL(scatter_k, dim3(gE), dim3(256), 0, stream, row, col, offs, cursor, ssrc, sw, dis, E);

    // weights: transpose + bf16 convert (both in one launch)
    hipLaunchKernelGGL(tcvt_k, dim3(1024), dim3(256), 0, stream, W2, w2t, W3, w3t);

    // layer 1 fused: h1 = relu((A_norm x) @ W1 + b1)
    hipLaunchKernelGGL(layer1_k, dim3(gW), dim3(256), 0, stream, xp, offs, ssrc, sw, dis,
                       W1, b1, bufX, N);

    // layer 2: agg1 = A_norm h1, h2 = relu(agg1 @ W2 + b2)
    hipLaunchKernelGGL(agg512w_k, dim3(gW), dim3(256), 0, stream, bufX, bufY, offs, ssrc, sw, dis,
                       (const float*)nullptr, 0, N);
    hipLaunchKernelGGL(mfma_gemm_k, dim3(nby8 * 8), dim3(256), 0, stream,
                       bufY, w2t, b2, bufZ, N, 1024, 512, 1, 3);

    // layer 3: g3 = h2 @ W3, h3 = relu(A_norm g3 + b3)
    hipLaunchKernelGGL(mfma_gemm_k, dim3(nby8 * 4), dim3(256), 0, stream,
                       bufZ, w3t, (const float*)nullptr, bufX, N, 512, 1024, 0, 2);
    hipLaunchKernelGGL(agg512w_k, dim3(gW), dim3(256), 0, stream, bufX, bufY, offs, ssrc, sw, dis,
                       b3, 1, N);

    // mean pool (+counts) + head
    hipLaunchKernelGGL(pool_k, dim3(256), dim3(256), 0, stream, bufY, batch, gsum, gcnt, N);
    hipLaunchKernelGGL(fc_k, dim3(NGRAPH), dim3(128), 0, stream, gsum, gcnt, fcw1, fcb1, fcw2, fcb2, out);
}

// Round 12
// 718.906 us; speedup vs baseline: 1.0064x; 1.0064x over previous
//
#include <hip/hip_runtime.h>
#include <hip/hip_bf16.h>

#define NNODES 50000
#define NEDGES 400000
#define NGRAPH 16

typedef __attribute__((ext_vector_type(4))) float floatx4;
typedef __attribute__((ext_vector_type(8))) short short8;

typedef __attribute__((address_space(3))) unsigned int lds_uint;
typedef __attribute__((address_space(1))) const unsigned int gbl_uint;

__device__ __forceinline__ void load16_to_lds(const void* g, void* l) {
    __builtin_amdgcn_global_load_lds((gbl_uint*)g, (lds_uint*)l, 16, 0, 0);
}

// ---------------------------------------------------------------------------
__global__ __launch_bounds__(64) void zero_out_k(float* out, int n) {
    int i = blockIdx.x * 64 + threadIdx.x;
    if (i < n) out[i] = 0.0f;
}

// init: zero counters/accumulators + pack x rows into float4
__global__ __launch_bounds__(256) void init_k(int* deg_cnt, int* cursor,
                                              float* gsum, int* gcnt,
                                              const float* __restrict__ x,
                                              float4* __restrict__ xp, int n) {
    int i = blockIdx.x * 256 + threadIdx.x;
    if (i < n) {
        deg_cnt[i] = 0; cursor[i] = 0;
        xp[i] = make_float4(x[i * 3 + 0], x[i * 3 + 1], x[i * 3 + 2], 0.0f);
    }
    if (i < NGRAPH * 512) gsum[i] = 0.0f;
    if (i < NGRAPH) gcnt[i] = 0;
}

__global__ __launch_bounds__(256) void deg_k(const int* __restrict__ col,
                                             int* __restrict__ deg_cnt, int e) {
    int i = blockIdx.x * 256 + threadIdx.x;
    if (i < e) atomicAdd(&deg_cnt[col[i]], 1);
}

// single-block exclusive scan of cnt -> offs[0..n] (+ fused dis = rsqrt(cnt+1))
__global__ __launch_bounds__(1024) void scan_k(const int* __restrict__ cnt,
                                               int* __restrict__ offs,
                                               float* __restrict__ dis, int n) {
    __shared__ int sbuf[1024];
    int t = threadIdx.x;
    int chunk = (n + 1023) / 1024;
    int beg = t * chunk;
    int end = min(beg + chunk, n);
    int s = 0;
    for (int i = beg; i < end; ++i) s += cnt[i];
    sbuf[t] = s;
    __syncthreads();
    for (int off = 1; off < 1024; off <<= 1) {
        int v = (t >= off) ? sbuf[t - off] : 0;
        __syncthreads();
        sbuf[t] += v;
        __syncthreads();
    }
    int run = sbuf[t] - s;
    for (int i = beg; i < end; ++i) {
        offs[i] = run;
        int c = cnt[i];
        dis[i] = rsqrtf((float)(c + 1));
        run += c;
    }
    if (t == 1023) offs[n] = sbuf[1023];
}

__global__ __launch_bounds__(256) void scatter_k(const int* __restrict__ row,
                                                 const int* __restrict__ col,
                                                 const int* __restrict__ offs,
                                                 int* __restrict__ cursor,
                                                 int* __restrict__ ssrc,
                                                 float* __restrict__ sw,
                                                 const float* __restrict__ dis, int e) {
    int i = blockIdx.x * 256 + threadIdx.x;
    if (i >= e) return;
    int d = col[i];
    int p = offs[d] + atomicAdd(&cursor[d], 1);
    int s = row[i];
    ssrc[p] = s;
    sw[p]   = dis[s];
}

// aggregate x (F=3): thread-per-node, float4 packed gathers (R8 structure)
__global__ __launch_bounds__(256) void agg3_k(const float4* __restrict__ xp,
                                              float* __restrict__ out,
                                              const int* __restrict__ offs,
                                              const int* __restrict__ ssrc,
                                              const float* __restrict__ sw,
                                              const float* __restrict__ dis, int n) {
    int d = blockIdx.x * 256 + threadIdx.x;
    if (d >= n) return;
    float dd = dis[d];
    float4 xd = xp[d];
    float a0 = dd * xd.x, a1 = dd * xd.y, a2 = dd * xd.z;
    int beg = offs[d], end = offs[d + 1];
    for (int e = beg; e < end; ++e) {
        int s = ssrc[e];
        float w = sw[e];
        float4 q = xp[s];
        a0 += w * q.x; a1 += w * q.y; a2 += w * q.z;
    }
    out[d * 3 + 0] = dd * a0;
    out[d * 3 + 1] = dd * a1;
    out[d * 3 + 2] = dd * a2;
}

// h1 = relu(aggx[N,3] @ W1[3,512] + b1) -> bf16; one WAVE per node (R8)
__global__ __launch_bounds__(256) void gemm1_k(const float* __restrict__ aggx,
                                               const float* __restrict__ W1,
                                               const float* __restrict__ b1,
                                               __hip_bfloat16* __restrict__ h1, int n) {
    int wave = threadIdx.x >> 6;
    int lane = threadIdx.x & 63;
    int d = blockIdx.x * 4 + wave;
    if (d >= n) return;
    float a0 = aggx[d * 3 + 0], a1 = aggx[d * 3 + 1], a2 = aggx[d * 3 + 2];
    int f0 = lane * 8;
    short8 ov;
#pragma unroll
    for (int j = 0; j < 8; ++j) {
        int f = f0 + j;
        float v = b1[f] + a0 * W1[f] + a1 * W1[512 + f] + a2 * W1[1024 + f];
        __hip_bfloat16 h = __float2bfloat16(fmaxf(v, 0.0f));
        ov[j] = *(short*)&h;
    }
    *(short8*)&h1[(size_t)d * 512 + f0] = ov;
}

__device__ inline float bs2f(short v) {
    return __uint_as_float(((unsigned int)(unsigned short)v) << 16);
}

// aggregation F=512 (R8 config — best measured): one WAVE per node,
// 16B loads, edge loop unrolled x4, fp32 acc, bf16 out.
__global__ __launch_bounds__(256) void agg512w_k(const __hip_bfloat16* __restrict__ in,
                                                 __hip_bfloat16* __restrict__ out,
                                                 const int* __restrict__ offs,
                                                 const int* __restrict__ ssrc,
                                                 const float* __restrict__ sw,
                                                 const float* __restrict__ dis,
                                                 const float* __restrict__ bias,
                                                 int relu, int n) {
    int wave = threadIdx.x >> 6;
    int lane = threadIdx.x & 63;
    int d = blockIdx.x * 4 + wave;
    if (d >= n) return;
    float dd = dis[d];
    short8 p = *(const short8*)&in[(size_t)d * 512 + lane * 8];
    float acc[8];
#pragma unroll
    for (int j = 0; j < 8; ++j) acc[j] = dd * bs2f(p[j]);

    int beg = offs[d], end = offs[d + 1];
    int e = beg;
    for (; e + 3 < end; e += 4) {
        int s0 = ssrc[e],     s1 = ssrc[e + 1];
        int s2 = ssrc[e + 2], s3 = ssrc[e + 3];
        float w0 = sw[e],     w1 = sw[e + 1];
        float w2 = sw[e + 2], w3 = sw[e + 3];
        short8 q0 = *(const short8*)&in[(size_t)s0 * 512 + lane * 8];
        short8 q1 = *(const short8*)&in[(size_t)s1 * 512 + lane * 8];
        short8 q2 = *(const short8*)&in[(size_t)s2 * 512 + lane * 8];
        short8 q3 = *(const short8*)&in[(size_t)s3 * 512 + lane * 8];
#pragma unroll
        for (int j = 0; j < 8; ++j) acc[j] += w0 * bs2f(q0[j]);
#pragma unroll
        for (int j = 0; j < 8; ++j) acc[j] += w1 * bs2f(q1[j]);
#pragma unroll
        for (int j = 0; j < 8; ++j) acc[j] += w2 * bs2f(q2[j]);
#pragma unroll
        for (int j = 0; j < 8; ++j) acc[j] += w3 * bs2f(q3[j]);
    }
    for (; e < end; ++e) {
        int s0 = ssrc[e];
        float w0 = sw[e];
        short8 q0 = *(const short8*)&in[(size_t)s0 * 512 + lane * 8];
#pragma unroll
        for (int j = 0; j < 8; ++j) acc[j] += w0 * bs2f(q0[j]);
    }

    short8 ov;
#pragma unroll
    for (int j = 0; j < 8; ++j) {
        float v = acc[j] * dd;
        if (bias) v += bias[lane * 8 + j];
        if (relu) v = fmaxf(v, 0.0f);
        __hip_bfloat16 h = __float2bfloat16(v);
        ov[j] = *(short*)&h;
    }
    *(short8*)&out[(size_t)d * 512 + lane * 8] = ov;
}

// merged transpose+convert for BOTH weight matrices, 1D-decoded
__global__ __launch_bounds__(256) void tcvt_k(const float* __restrict__ W2,
                                              __hip_bfloat16* __restrict__ w2t,
                                              const float* __restrict__ W3,
                                              __hip_bfloat16* __restrict__ w3t) {
    __shared__ float tile[32][33];
    int t = threadIdx.x;
    const float* W; __hip_bfloat16* Wt;
    int K, N, idx;
    if (blockIdx.x < 512) { W = W2; Wt = w2t; K = 512;  N = 1024; idx = blockIdx.x; }
    else                  { W = W3; Wt = w3t; K = 1024; N = 512;  idx = blockIdx.x - 512; }
    int nbn = N / 32;
    int bn = (idx % nbn) * 32;
    int bk = (idx / nbn) * 32;
    int c = t & 31, r0 = t >> 5;
#pragma unroll
    for (int j = 0; j < 4; ++j) {
        int r = r0 + j * 8;
        tile[r][c] = W[(size_t)(bk + r) * N + bn + c];
    }
    __syncthreads();
#pragma unroll
    for (int j = 0; j < 4; ++j) {
        int r = r0 + j * 8;
        Wt[(size_t)(bn + r) * K + bk + c] = __float2bfloat16(tile[c][r]);
    }
}

// bf16 MFMA GEMM (R8 config — best measured): C[M,N] = epi(A@Bt^T + bias)
// 128x128 tile, BK=32, 4 waves, fragment-major global_load_lds staging,
// double-buffered, 1 barrier/iter, XCD swizzle, 4 blocks/CU.
__global__ __launch_bounds__(256, 4) void mfma_gemm_k(const __hip_bfloat16* __restrict__ A,
                                                      const __hip_bfloat16* __restrict__ Bt,
                                                      const float* __restrict__ bias,
                                                      __hip_bfloat16* __restrict__ C,
                                                      int M, int N, int K, int relu,
                                                      int lnbx) {
    __shared__ short smem[17408];

    int tid  = threadIdx.x;
    int lane = tid & 63;
    int wave = tid >> 6;
    int wm = (wave >> 1) * 64;
    int wn = (wave & 1) * 64;
    int fr = lane & 15;
    int kg = lane >> 4;

    int b  = blockIdx.x;
    int r8 = b & 7;
    int j  = (b >> 3) & ((1 << lnbx) - 1);
    int g8 = b >> (3 + lnbx);
    int bm = (g8 * 8 + r8) * 128;
    int bn = j * 128;

    const __hip_bfloat16* gbase;
    if (wave < 2) gbase = A  + (size_t)(bm + wave * 64 + fr) * K;
    else          gbase = Bt + (size_t)(bn + (wave - 2) * 64 + fr) * K;
    gbase += kg * 8;
    size_t segstr = (size_t)16 * K;

    floatx4 acc[4][4] = {};

#pragma unroll
    for (int i = 0; i < 4; ++i)
        load16_to_lds(gbase + i * segstr, &smem[(wave * 4 + i) * 512]);
    gbase += 32;

    int cur = 0;
    for (int k0 = 0; k0 < K; k0 += 32) {
        __syncthreads();
        int nxt = cur ^ 8192;
        if (k0 + 32 < K) {
#pragma unroll
            for (int i = 0; i < 4; ++i)
                load16_to_lds(gbase + i * segstr, &smem[nxt + (wave * 4 + i) * 512]);
            gbase += 32;
        }

        short8 af[4], bf[4];
#pragma unroll
        for (int mi = 0; mi < 4; ++mi)
            af[mi] = *(short8*)&smem[cur + ((wm >> 4) + mi) * 512 + lane * 8];
#pragma unroll
        for (int ni = 0; ni < 4; ++ni)
            bf[ni] = *(short8*)&smem[cur + (8 + (wn >> 4) + ni) * 512 + lane * 8];
#pragma unroll
        for (int mi = 0; mi < 4; ++mi)
#pragma unroll
            for (int ni = 0; ni < 4; ++ni)
                acc[mi][ni] = __builtin_amdgcn_mfma_f32_16x16x32_bf16(
                    af[mi], bf[ni], acc[mi][ni], 0, 0, 0);
        cur = nxt;
    }
    __syncthreads();

    short* Cs = smem;
#pragma unroll
    for (int mi = 0; mi < 4; ++mi) {
#pragma unroll
        for (int ni = 0; ni < 4; ++ni) {
            int rl = wm + mi * 16 + (lane >> 4) * 4;
            int cl = wn + ni * 16 + (lane & 15);
            float bv = bias ? bias[bn + cl] : 0.0f;
#pragma unroll
            for (int r = 0; r < 4; ++r) {
                float v = acc[mi][ni][r] + bv;
                if (relu) v = fmaxf(v, 0.0f);
                __hip_bfloat16 h = __float2bfloat16(v);
                Cs[(rl + r) * 136 + cl] = *(short*)&h;
            }
        }
    }
    __syncthreads();
#pragma unroll
    for (int i = 0; i < 8; ++i) {
        int c  = tid + 256 * i;
        int rr = c >> 4;
        int cc = c & 15;
        int grow = bm + rr;
        if (grow < M)
            *(short8*)&C[(size_t)grow * N + bn + cc * 8] =
                *(short8*)&Cs[rr * 136 + cc * 8];
    }
}

// pooled sums (bf16 input, LDS fp32 accumulators) + fused per-graph counts
__global__ __launch_bounds__(256) void pool_k(const __hip_bfloat16* __restrict__ h,
                                              const int* __restrict__ batch,
                                              float* __restrict__ gsum,
                                              int* __restrict__ gcnt, int n) {
    __shared__ float ls[NGRAPH * 512];
    __shared__ int lcnt[NGRAPH];
    int t = threadIdx.x;
    for (int i = t; i < NGRAPH * 512; i += 256) ls[i] = 0.0f;
    if (t < NGRAPH) lcnt[t] = 0;
    __syncthreads();
    for (int d = blockIdx.x; d < n; d += gridDim.x) {
        int g = batch[d];
        if (t == 0) atomicAdd(&lcnt[g], 1);
        unsigned int q = *(const unsigned int*)&h[(size_t)d * 512 + 2 * t];
        ls[g * 512 + 2 * t]     += __uint_as_float((q & 0xffffu) << 16);
        ls[g * 512 + 2 * t + 1] += __uint_as_float((q >> 16) << 16);
    }
    __syncthreads();
    for (int i = t; i < NGRAPH * 512; i += 256) atomicAdd(&gsum[i], ls[i]);
    if (t < NGRAPH) atomicAdd(&gcnt[t], lcnt[t]);
}

// head MLP (fp32)
__global__ __launch_bounds__(128) void fc_k(const float* __restrict__ gsum,
                                            const int* __restrict__ gcnt,
                                            const float* __restrict__ fcw1,
                                            const float* __restrict__ fcb1,
                                            const float* __restrict__ fcw2,
                                            const float* __restrict__ fcb2,
                                            float* __restrict__ out) {
    int g = blockIdx.x;
    int t = threadIdx.x;  // 128
    __shared__ float pooled[512];
    __shared__ float red[128];
    float inv = 1.0f / fmaxf((float)gcnt[g], 1.0f);
    for (int i = t; i < 512; i += 128) pooled[i] = gsum[g * 512 + i] * inv;
    __syncthreads();
    float s = fcb1[t];
    for (int k = 0; k < 512; ++k) s += pooled[k] * fcw1[k * 128 + t];
    s = fmaxf(s, 0.0f);
    red[t] = s * fcw2[t];
    __syncthreads();
    for (int off = 64; off > 0; off >>= 1) {
        if (t < off) red[t] += red[t + off];
        __syncthreads();
    }
    if (t == 0) out[g] = red[0] + fcb2[0];
}

extern "C" void kernel_launch(void* const* d_in, const int* in_sizes, int n_in,
                              void* d_out, int out_size, void* d_ws, size_t ws_size,
                              hipStream_t stream) {
    const float* x    = (const float*)d_in[0];
    const int*   ei   = (const int*)d_in[1];   // [2, E]
    const int*   batch= (const int*)d_in[2];
    const float* W1   = (const float*)d_in[3];
    const float* b1   = (const float*)d_in[4];
    const float* W2   = (const float*)d_in[5];
    const float* b2   = (const float*)d_in[6];
    const float* W3   = (const float*)d_in[7];
    const float* b3   = (const float*)d_in[8];
    const float* fcw1 = (const float*)d_in[9];
    const float* fcb1 = (const float*)d_in[10];
    const float* fcw2 = (const float*)d_in[11];
    const float* fcb2 = (const float*)d_in[12];
    float* out = (float*)d_out;

    const int N = in_sizes[0] / 3;      // 50000
    const int E = in_sizes[1] / 2;      // 400000
    const int Mpad = (N + 127) & ~127;  // GEMM A reads unguarded to Mpad
    const int* row = ei;
    const int* col = ei + E;

    // ---- workspace layout ----
    size_t used = 0;
    auto need = [&](size_t bytes) {
        size_t off = used;
        used += (bytes + 255) & ~(size_t)255;
        return off;
    };
    size_t o_deg  = need((size_t)N * 4);
    size_t o_cur  = need((size_t)N * 4);
    size_t o_dis  = need((size_t)N * 4);
    size_t o_offs = need((size_t)(N + 1) * 4);
    size_t o_ssrc = need((size_t)E * 4);
    size_t o_sw   = need((size_t)E * 4);
    size_t o_xp   = need((size_t)N * 16);            // packed x float4
    size_t o_aggx = need((size_t)N * 3 * 4);
    size_t o_gsum = need((size_t)NGRAPH * 512 * 4);
    size_t o_gcnt = need((size_t)NGRAPH * 4);
    size_t o_w2t  = need((size_t)512 * 1024 * 2);    // W2^T bf16
    size_t o_w3t  = need((size_t)1024 * 512 * 2);    // W3^T bf16
    size_t o_bufX = need((size_t)Mpad * 512 * 2);    // h1 -> g3   (bf16)
    size_t o_bufY = need((size_t)Mpad * 512 * 2);    // agg1 -> h3 (bf16)
    size_t o_bufZ = need((size_t)Mpad * 1024 * 2);   // h2         (bf16)

    if (used > ws_size) {
        hipLaunchKernelGGL(zero_out_k, dim3((out_size + 63) / 64), dim3(64), 0, stream,
                           out, out_size);
        return;
    }

    char* base = (char*)d_ws;
    int*    deg_cnt = (int*)   (base + o_deg);
    int*    cursor  = (int*)   (base + o_cur);
    float*  dis     = (float*) (base + o_dis);
    int*    offs    = (int*)   (base + o_offs);
    int*    ssrc    = (int*)   (base + o_ssrc);
    float*  sw      = (float*) (base + o_sw);
    float4* xp      = (float4*)(base + o_xp);
    float*  aggx    = (float*) (base + o_aggx);
    float*  gsum    = (float*) (base + o_gsum);
    int*    gcnt    = (int*)   (base + o_gcnt);
    __hip_bfloat16* w2t  = (__hip_bfloat16*)(base + o_w2t);
    __hip_bfloat16* w3t  = (__hip_bfloat16*)(base + o_w3t);
    __hip_bfloat16* bufX = (__hip_bfloat16*)(base + o_bufX);
    __hip_bfloat16* bufY = (__hip_bfloat16*)(base + o_bufY);
    __hip_bfloat16* bufZ = (__hip_bfloat16*)(base + o_bufZ);
    (void)n_in;

    int gN = (N + 255) / 256;
    int gE = (E + 255) / 256;
    int gW = (N + 3) / 4;                         // wave-per-node grids
    int nby8 = (((N + 127) / 128 + 7) / 8) * 8;   // 128-row tiles, padded to x8

    // CSR build (+x packing, +dis fused into scan)
    hipLaunchKernelGGL(init_k, dim3(gN), dim3(256), 0, stream, deg_cnt, cursor, gsum, gcnt, x, xp, N);
    hipLaunchKernelGGL(deg_k, dim3(gE), dim3(256), 0, stream, col, deg_cnt, E);
    hipLaunchKernelGGL(scan_k, dim3(1), dim3(1024), 0, stream, deg_cnt, offs, dis, N);
    hipLaunchKernelGGL(scatter_k, dim3(gE), dim3(256), 0, stream, row, col, offs, cursor, ssrc, sw, dis, E);

    // weights: transpose + bf16 convert (both in one launch)
    hipLaunchKernelGGL(tcvt_k, dim3(1024), dim3(256), 0, stream, W2, w2t, W3, w3t);

    // layer 1: agg(F=3) thread-per-node, then 3->512 GEMM wave-per-node
    hipLaunchKernelGGL(agg3_k, dim3(gN), dim3(256), 0, stream, xp, aggx, offs, ssrc, sw, dis, N);
    hipLaunchKernelGGL(gemm1_k, dim3(gW), dim3(256), 0, stream, aggx, W1, b1, bufX, N);

    // layer 2: agg1 = A_norm h1, h2 = relu(agg1 @ W2 + b2)
    hipLaunchKernelGGL(agg512w_k, dim3(gW), dim3(256), 0, stream, bufX, bufY, offs, ssrc, sw, dis,
                       (const float*)nullptr, 0, N);
    hipLaunchKernelGGL(mfma_gemm_k, dim3(nby8 * 8), dim3(256), 0, stream,
                       bufY, w2t, b2, bufZ, N, 1024, 512, 1, 3);

    // layer 3: g3 = h2 @ W3, h3 = relu(A_norm g3 + b3)
    hipLaunchKernelGGL(mfma_gemm_k, dim3(nby8 * 4), dim3(256), 0, stream,
                       bufZ, w3t, (const float*)nullptr, bufX, N, 512, 1024, 0, 2);
    hipLaunchKernelGGL(agg512w_k, dim3(gW), dim3(256), 0, stream, bufX, bufY, offs, ssrc, sw, dis,
                       b3, 1, N);

    // mean pool (+counts) + head
    hipLaunchKernelGGL(pool_k, dim3(256), dim3(256), 0, stream, bufY, batch, gsum, gcnt, N);
    hipLaunchKernelGGL(fc_k, dim3(NGRAPH), dim3(128), 0, stream, gsum, gcnt, fcw1, fcb1, fcw2, fcb2, out);
}

// Round 13
// 632.154 us; speedup vs baseline: 1.1445x; 1.1372x over previous
//
#include <hip/hip_runtime.h>
#include <hip/hip_bf16.h>

#define NNODES 50000
#define NEDGES 400000
#define NGRAPH 16

typedef __attribute__((ext_vector_type(4))) float floatx4;
typedef __attribute__((ext_vector_type(8))) short short8;

typedef __attribute__((address_space(3))) unsigned int lds_uint;
typedef __attribute__((address_space(1))) const unsigned int gbl_uint;

__device__ __forceinline__ void load16_to_lds(const void* g, void* l) {
    __builtin_amdgcn_global_load_lds((gbl_uint*)g, (lds_uint*)l, 16, 0, 0);
}

// ---------------------------------------------------------------------------
__global__ __launch_bounds__(64) void zero_out_k(float* out, int n) {
    int i = blockIdx.x * 64 + threadIdx.x;
    if (i < n) out[i] = 0.0f;
}

// init: zero counters/accumulators + pack x rows into float4
__global__ __launch_bounds__(256) void init_k(int* deg_cnt, int* cursor,
                                              float* gsum, int* gcnt,
                                              const float* __restrict__ x,
                                              float4* __restrict__ xp, int n) {
    int i = blockIdx.x * 256 + threadIdx.x;
    if (i < n) {
        deg_cnt[i] = 0; cursor[i] = 0;
        xp[i] = make_float4(x[i * 3 + 0], x[i * 3 + 1], x[i * 3 + 2], 0.0f);
    }
    if (i < NGRAPH * 512) gsum[i] = 0.0f;
    if (i < NGRAPH) gcnt[i] = 0;
}

__global__ __launch_bounds__(256) void deg_k(const int* __restrict__ col,
                                             int* __restrict__ deg_cnt, int e) {
    int i = blockIdx.x * 256 + threadIdx.x;
    if (i < e) atomicAdd(&deg_cnt[col[i]], 1);
}

// ---- parallel 3-phase scan (replaces single-block scan_k) ----
// phase 1: per-1024-segment sums
__global__ __launch_bounds__(256) void segsum_k(const int* __restrict__ cnt,
                                                int* __restrict__ segsum, int n) {
    __shared__ int sb[256];
    int seg = blockIdx.x;
    int base = seg * 1024;
    int t = threadIdx.x;
    int s = 0;
#pragma unroll
    for (int j = 0; j < 4; ++j) {
        int idx = base + t + j * 256;
        if (idx < n) s += cnt[idx];
    }
    sb[t] = s;
    __syncthreads();
    for (int off = 128; off > 0; off >>= 1) {
        if (t < off) sb[t] += sb[t + off];
        __syncthreads();
    }
    if (t == 0) segsum[seg] = sb[0];
}

// phase 2: exclusive scan of nseg segment sums (tiny); writes offs[n]=total
__global__ __launch_bounds__(64) void segscan_k(const int* __restrict__ segsum,
                                                int* __restrict__ segbase,
                                                int* __restrict__ offs,
                                                int nseg, int n) {
    if (threadIdx.x == 0) {
        int run = 0;
        for (int s = 0; s < nseg; ++s) { segbase[s] = run; run += segsum[s]; }
        offs[n] = run;
    }
}

// phase 3: local exclusive scan within each segment + emit offs and dis
__global__ __launch_bounds__(1024) void offs_k(const int* __restrict__ cnt,
                                               const int* __restrict__ segbase,
                                               int* __restrict__ offs,
                                               float* __restrict__ dis, int n) {
    __shared__ int sb[1024];
    int seg = blockIdx.x;
    int t = threadIdx.x;
    int i = seg * 1024 + t;
    int c = (i < n) ? cnt[i] : 0;
    sb[t] = c;
    __syncthreads();
    for (int off = 1; off < 1024; off <<= 1) {
        int v = (t >= off) ? sb[t - off] : 0;
        __syncthreads();
        sb[t] += v;
        __syncthreads();
    }
    if (i < n) {
        offs[i] = segbase[seg] + sb[t] - c;   // exclusive prefix
        dis[i]  = rsqrtf((float)(c + 1));
    }
}

__global__ __launch_bounds__(256) void scatter_k(const int* __restrict__ row,
                                                 const int* __restrict__ col,
                                                 const int* __restrict__ offs,
                                                 int* __restrict__ cursor,
                                                 int* __restrict__ ssrc,
                                                 float* __restrict__ sw,
                                                 const float* __restrict__ dis, int e) {
    int i = blockIdx.x * 256 + threadIdx.x;
    if (i >= e) return;
    int d = col[i];
    int p = offs[d] + atomicAdd(&cursor[d], 1);
    int s = row[i];
    ssrc[p] = s;
    sw[p]   = dis[s];
}

// aggregate x (F=3): thread-per-node, float4 packed gathers
__global__ __launch_bounds__(256) void agg3_k(const float4* __restrict__ xp,
                                              float* __restrict__ out,
                                              const int* __restrict__ offs,
                                              const int* __restrict__ ssrc,
                                              const float* __restrict__ sw,
                                              const float* __restrict__ dis, int n) {
    int d = blockIdx.x * 256 + threadIdx.x;
    if (d >= n) return;
    float dd = dis[d];
    float4 xd = xp[d];
    float a0 = dd * xd.x, a1 = dd * xd.y, a2 = dd * xd.z;
    int beg = offs[d], end = offs[d + 1];
    for (int e = beg; e < end; ++e) {
        int s = ssrc[e];
        float w = sw[e];
        float4 q = xp[s];
        a0 += w * q.x; a1 += w * q.y; a2 += w * q.z;
    }
    out[d * 3 + 0] = dd * a0;
    out[d * 3 + 1] = dd * a1;
    out[d * 3 + 2] = dd * a2;
}

// h1 = relu(aggx[N,3] @ W1[3,512] + b1) -> bf16; one WAVE per node
__global__ __launch_bounds__(256) void gemm1_k(const float* __restrict__ aggx,
                                               const float* __restrict__ W1,
                                               const float* __restrict__ b1,
                                               __hip_bfloat16* __restrict__ h1, int n) {
    int wave = threadIdx.x >> 6;
    int lane = threadIdx.x & 63;
    int d = blockIdx.x * 4 + wave;
    if (d >= n) return;
    float a0 = aggx[d * 3 + 0], a1 = aggx[d * 3 + 1], a2 = aggx[d * 3 + 2];
    int f0 = lane * 8;
    short8 ov;
#pragma unroll
    for (int j = 0; j < 8; ++j) {
        int f = f0 + j;
        float v = b1[f] + a0 * W1[f] + a1 * W1[512 + f] + a2 * W1[1024 + f];
        __hip_bfloat16 h = __float2bfloat16(fmaxf(v, 0.0f));
        ov[j] = *(short*)&h;
    }
    *(short8*)&h1[(size_t)d * 512 + f0] = ov;
}

__device__ inline float bs2f(short v) {
    return __uint_as_float(((unsigned int)(unsigned short)v) << 16);
}

// aggregation F=512 (R8 config — best measured): one WAVE per node,
// 16B loads, edge loop unrolled x4, fp32 acc, bf16 out.
__global__ __launch_bounds__(256) void agg512w_k(const __hip_bfloat16* __restrict__ in,
                                                 __hip_bfloat16* __restrict__ out,
                                                 const int* __restrict__ offs,
                                                 const int* __restrict__ ssrc,
                                                 const float* __restrict__ sw,
                                                 const float* __restrict__ dis,
                                                 const float* __restrict__ bias,
                                                 int relu, int n) {
    int wave = threadIdx.x >> 6;
    int lane = threadIdx.x & 63;
    int d = blockIdx.x * 4 + wave;
    if (d >= n) return;
    float dd = dis[d];
    short8 p = *(const short8*)&in[(size_t)d * 512 + lane * 8];
    float acc[8];
#pragma unroll
    for (int j = 0; j < 8; ++j) acc[j] = dd * bs2f(p[j]);

    int beg = offs[d], end = offs[d + 1];
    int e = beg;
    for (; e + 3 < end; e += 4) {
        int s0 = ssrc[e],     s1 = ssrc[e + 1];
        int s2 = ssrc[e + 2], s3 = ssrc[e + 3];
        float w0 = sw[e],     w1 = sw[e + 1];
        float w2 = sw[e + 2], w3 = sw[e + 3];
        short8 q0 = *(const short8*)&in[(size_t)s0 * 512 + lane * 8];
        short8 q1 = *(const short8*)&in[(size_t)s1 * 512 + lane * 8];
        short8 q2 = *(const short8*)&in[(size_t)s2 * 512 + lane * 8];
        short8 q3 = *(const short8*)&in[(size_t)s3 * 512 + lane * 8];
#pragma unroll
        for (int j = 0; j < 8; ++j) acc[j] += w0 * bs2f(q0[j]);
#pragma unroll
        for (int j = 0; j < 8; ++j) acc[j] += w1 * bs2f(q1[j]);
#pragma unroll
        for (int j = 0; j < 8; ++j) acc[j] += w2 * bs2f(q2[j]);
#pragma unroll
        for (int j = 0; j < 8; ++j) acc[j] += w3 * bs2f(q3[j]);
    }
    for (; e < end; ++e) {
        int s0 = ssrc[e];
        float w0 = sw[e];
        short8 q0 = *(const short8*)&in[(size_t)s0 * 512 + lane * 8];
#pragma unroll
        for (int j = 0; j < 8; ++j) acc[j] += w0 * bs2f(q0[j]);
    }

    short8 ov;
#pragma unroll
    for (int j = 0; j < 8; ++j) {
        float v = acc[j] * dd;
        if (bias) v += bias[lane * 8 + j];
        if (relu) v = fmaxf(v, 0.0f);
        __hip_bfloat16 h = __float2bfloat16(v);
        ov[j] = *(short*)&h;
    }
    *(short8*)&out[(size_t)d * 512 + lane * 8] = ov;
}

// merged transpose+convert for BOTH weight matrices, 1D-decoded
__global__ __launch_bounds__(256) void tcvt_k(const float* __restrict__ W2,
                                              __hip_bfloat16* __restrict__ w2t,
                                              const float* __restrict__ W3,
                                              __hip_bfloat16* __restrict__ w3t) {
    __shared__ float tile[32][33];
    int t = threadIdx.x;
    const float* W; __hip_bfloat16* Wt;
    int K, N, idx;
    if (blockIdx.x < 512) { W = W2; Wt = w2t; K = 512;  N = 1024; idx = blockIdx.x; }
    else                  { W = W3; Wt = w3t; K = 1024; N = 512;  idx = blockIdx.x - 512; }
    int nbn = N / 32;
    int bn = (idx % nbn) * 32;
    int bk = (idx / nbn) * 32;
    int c = t & 31, r0 = t >> 5;
#pragma unroll
    for (int j = 0; j < 4; ++j) {
        int r = r0 + j * 8;
        tile[r][c] = W[(size_t)(bk + r) * N + bn + c];
    }
    __syncthreads();
#pragma unroll
    for (int j = 0; j < 4; ++j) {
        int r = r0 + j * 8;
        Wt[(size_t)(bn + r) * K + bk + c] = __float2bfloat16(tile[c][r]);
    }
}

// bf16 MFMA GEMM (R8 config — best measured): C[M,N] = epi(A@Bt^T + bias)
// 128x128 tile, BK=32, 4 waves, fragment-major global_load_lds staging,
// double-buffered, 1 barrier/iter, XCD swizzle, 4 blocks/CU.
__global__ __launch_bounds__(256, 4) void mfma_gemm_k(const __hip_bfloat16* __restrict__ A,
                                                      const __hip_bfloat16* __restrict__ Bt,
                                                      const float* __restrict__ bias,
                                                      __hip_bfloat16* __restrict__ C,
                                                      int M, int N, int K, int relu,
                                                      int lnbx) {
    __shared__ short smem[17408];

    int tid  = threadIdx.x;
    int lane = tid & 63;
    int wave = tid >> 6;
    int wm = (wave >> 1) * 64;
    int wn = (wave & 1) * 64;
    int fr = lane & 15;
    int kg = lane >> 4;

    int b  = blockIdx.x;
    int r8 = b & 7;
    int j  = (b >> 3) & ((1 << lnbx) - 1);
    int g8 = b >> (3 + lnbx);
    int bm = (g8 * 8 + r8) * 128;
    int bn = j * 128;

    const __hip_bfloat16* gbase;
    if (wave < 2) gbase = A  + (size_t)(bm + wave * 64 + fr) * K;
    else          gbase = Bt + (size_t)(bn + (wave - 2) * 64 + fr) * K;
    gbase += kg * 8;
    size_t segstr = (size_t)16 * K;

    floatx4 acc[4][4] = {};

#pragma unroll
    for (int i = 0; i < 4; ++i)
        load16_to_lds(gbase + i * segstr, &smem[(wave * 4 + i) * 512]);
    gbase += 32;

    int cur = 0;
    for (int k0 = 0; k0 < K; k0 += 32) {
        __syncthreads();
        int nxt = cur ^ 8192;
        if (k0 + 32 < K) {
#pragma unroll
            for (int i = 0; i < 4; ++i)
                load16_to_lds(gbase + i * segstr, &smem[nxt + (wave * 4 + i) * 512]);
            gbase += 32;
        }

        short8 af[4], bf[4];
#pragma unroll
        for (int mi = 0; mi < 4; ++mi)
            af[mi] = *(short8*)&smem[cur + ((wm >> 4) + mi) * 512 + lane * 8];
#pragma unroll
        for (int ni = 0; ni < 4; ++ni)
            bf[ni] = *(short8*)&smem[cur + (8 + (wn >> 4) + ni) * 512 + lane * 8];
#pragma unroll
        for (int mi = 0; mi < 4; ++mi)
#pragma unroll
            for (int ni = 0; ni < 4; ++ni)
                acc[mi][ni] = __builtin_amdgcn_mfma_f32_16x16x32_bf16(
                    af[mi], bf[ni], acc[mi][ni], 0, 0, 0);
        cur = nxt;
    }
    __syncthreads();

    short* Cs = smem;
#pragma unroll
    for (int mi = 0; mi < 4; ++mi) {
#pragma unroll
        for (int ni = 0; ni < 4; ++ni) {
            int rl = wm + mi * 16 + (lane >> 4) * 4;
            int cl = wn + ni * 16 + (lane & 15);
            float bv = bias ? bias[bn + cl] : 0.0f;
#pragma unroll
            for (int r = 0; r < 4; ++r) {
                float v = acc[mi][ni][r] + bv;
                if (relu) v = fmaxf(v, 0.0f);
                __hip_bfloat16 h = __float2bfloat16(v);
                Cs[(rl + r) * 136 + cl] = *(short*)&h;
            }
        }
    }
    __syncthreads();
#pragma unroll
    for (int i = 0; i < 8; ++i) {
        int c  = tid + 256 * i;
        int rr = c >> 4;
        int cc = c & 15;
        int grow = bm + rr;
        if (grow < M)
            *(short8*)&C[(size_t)grow * N + bn + cc * 8] =
                *(short8*)&Cs[rr * 136 + cc * 8];
    }
}

// pooled sums (bf16 input, LDS fp32 accumulators) + fused per-graph counts
__global__ __launch_bounds__(256) void pool_k(const __hip_bfloat16* __restrict__ h,
                                              const int* __restrict__ batch,
                                              float* __restrict__ gsum,
                                              int* __restrict__ gcnt, int n) {
    __shared__ float ls[NGRAPH * 512];
    __shared__ int lcnt[NGRAPH];
    int t = threadIdx.x;
    for (int i = t; i < NGRAPH * 512; i += 256) ls[i] = 0.0f;
    if (t < NGRAPH) lcnt[t] = 0;
    __syncthreads();
    for (int d = blockIdx.x; d < n; d += gridDim.x) {
        int g = batch[d];
        if (t == 0) atomicAdd(&lcnt[g], 1);
        unsigned int q = *(const unsigned int*)&h[(size_t)d * 512 + 2 * t];
        ls[g * 512 + 2 * t]     += __uint_as_float((q & 0xffffu) << 16);
        ls[g * 512 + 2 * t + 1] += __uint_as_float((q >> 16) << 16);
    }
    __syncthreads();
    for (int i = t; i < NGRAPH * 512; i += 256) atomicAdd(&gsum[i], ls[i]);
    if (t < NGRAPH) atomicAdd(&gcnt[t], lcnt[t]);
}

// head MLP (fp32)
__global__ __launch_bounds__(128) void fc_k(const float* __restrict__ gsum,
                                            const int* __restrict__ gcnt,
                                            const float* __restrict__ fcw1,
                                            const float* __restrict__ fcb1,
                                            const float* __restrict__ fcw2,
                                            const float* __restrict__ fcb2,
                                            float* __restrict__ out) {
    int g = blockIdx.x;
    int t = threadIdx.x;  // 128
    __shared__ float pooled[512];
    __shared__ float red[128];
    float inv = 1.0f / fmaxf((float)gcnt[g], 1.0f);
    for (int i = t; i < 512; i += 128) pooled[i] = gsum[g * 512 + i] * inv;
    __syncthreads();
    float s = fcb1[t];
    for (int k = 0; k < 512; ++k) s += pooled[k] * fcw1[k * 128 + t];
    s = fmaxf(s, 0.0f);
    red[t] = s * fcw2[t];
    __syncthreads();
    for (int off = 64; off > 0; off >>= 1) {
        if (t < off) red[t] += red[t + off];
        __syncthreads();
    }
    if (t == 0) out[g] = red[0] + fcb2[0];
}

extern "C" void kernel_launch(void* const* d_in, const int* in_sizes, int n_in,
                              void* d_out, int out_size, void* d_ws, size_t ws_size,
                              hipStream_t stream) {
    const float* x    = (const float*)d_in[0];
    const int*   ei   = (const int*)d_in[1];   // [2, E]
    const int*   batch= (const int*)d_in[2];
    const float* W1   = (const float*)d_in[3];
    const float* b1   = (const float*)d_in[4];
    const float* W2   = (const float*)d_in[5];
    const float* b2   = (const float*)d_in[6];
    const float* W3   = (const float*)d_in[7];
    const float* b3   = (const float*)d_in[8];
    const float* fcw1 = (const float*)d_in[9];
    const float* fcb1 = (const float*)d_in[10];
    const float* fcw2 = (const float*)d_in[11];
    const float* fcb2 = (const float*)d_in[12];
    float* out = (float*)d_out;

    const int N = in_sizes[0] / 3;      // 50000
    const int E = in_sizes[1] / 2;      // 400000
    const int Mpad = (N + 127) & ~127;  // GEMM A reads unguarded to Mpad
    const int nseg = (N + 1023) / 1024; // scan segments
    const int* row = ei;
    const int* col = ei + E;

    // ---- workspace layout ----
    size_t used = 0;
    auto need = [&](size_t bytes) {
        size_t off = used;
        used += (bytes + 255) & ~(size_t)255;
        return off;
    };
    size_t o_deg  = need((size_t)N * 4);
    size_t o_cur  = need((size_t)N * 4);
    size_t o_dis  = need((size_t)N * 4);
    size_t o_offs = need((size_t)(N + 1) * 4);
    size_t o_seg  = need((size_t)nseg * 4);          // segment sums
    size_t o_segb = need((size_t)nseg * 4);          // segment bases
    size_t o_ssrc = need((size_t)E * 4);
    size_t o_sw   = need((size_t)E * 4);
    size_t o_xp   = need((size_t)N * 16);            // packed x float4
    size_t o_aggx = need((size_t)N * 3 * 4);
    size_t o_gsum = need((size_t)NGRAPH * 512 * 4);
    size_t o_gcnt = need((size_t)NGRAPH * 4);
    size_t o_w2t  = need((size_t)512 * 1024 * 2);    // W2^T bf16
    size_t o_w3t  = need((size_t)1024 * 512 * 2);    // W3^T bf16
    size_t o_bufX = need((size_t)Mpad * 512 * 2);    // h1 -> g3   (bf16)
    size_t o_bufY = need((size_t)Mpad * 512 * 2);    // agg1 -> h3 (bf16)
    size_t o_bufZ = need((size_t)Mpad * 1024 * 2);   // h2         (bf16)

    if (used > ws_size) {
        hipLaunchKernelGGL(zero_out_k, dim3((out_size + 63) / 64), dim3(64), 0, stream,
                           out, out_size);
        return;
    }

    char* base = (char*)d_ws;
    int*    deg_cnt = (int*)   (base + o_deg);
    int*    cursor  = (int*)   (base + o_cur);
    float*  dis     = (float*) (base + o_dis);
    int*    offs    = (int*)   (base + o_offs);
    int*    segsum  = (int*)   (base + o_seg);
    int*    segbase = (int*)   (base + o_segb);
    int*    ssrc    = (int*)   (base + o_ssrc);
    float*  sw      = (float*) (base + o_sw);
    float4* xp      = (float4*)(base + o_xp);
    float*  aggx    = (float*) (base + o_aggx);
    float*  gsum    = (float*) (base + o_gsum);
    int*    gcnt    = (int*)   (base + o_gcnt);
    __hip_bfloat16* w2t  = (__hip_bfloat16*)(base + o_w2t);
    __hip_bfloat16* w3t  = (__hip_bfloat16*)(base + o_w3t);
    __hip_bfloat16* bufX = (__hip_bfloat16*)(base + o_bufX);
    __hip_bfloat16* bufY = (__hip_bfloat16*)(base + o_bufY);
    __hip_bfloat16* bufZ = (__hip_bfloat16*)(base + o_bufZ);
    (void)n_in;

    int gN = (N + 255) / 256;
    int gE = (E + 255) / 256;
    int gW = (N + 3) / 4;                         // wave-per-node grids
    int nby8 = (((N + 127) / 128 + 7) / 8) * 8;   // 128-row tiles, padded to x8

    // CSR build (+x packing); parallel 3-phase scan
    hipLaunchKernelGGL(init_k, dim3(gN), dim3(256), 0, stream, deg_cnt, cursor, gsum, gcnt, x, xp, N);
    hipLaunchKernelGGL(deg_k, dim3(gE), dim3(256), 0, stream, col, deg_cnt, E);
    hipLaunchKernelGGL(segsum_k, dim3(nseg), dim3(256), 0, stream, deg_cnt, segsum, N);
    hipLaunchKernelGGL(segscan_k, dim3(1), dim3(64), 0, stream, segsum, segbase, offs, nseg, N);
    hipLaunchKernelGGL(offs_k, dim3(nseg), dim3(1024), 0, stream, deg_cnt, segbase, offs, dis, N);
    hipLaunchKernelGGL(scatter_k, dim3(gE), dim3(256), 0, stream, row, col, offs, cursor, ssrc, sw, dis, E);

    // weights: transpose + bf16 convert (both in one launch)
    hipLaunchKernelGGL(tcvt_k, dim3(1024), dim3(256), 0, stream, W2, w2t, W3, w3t);

    // layer 1: agg(F=3) thread-per-node, then 3->512 GEMM wave-per-node
    hipLaunchKernelGGL(agg3_k, dim3(gN), dim3(256), 0, stream, xp, aggx, offs, ssrc, sw, dis, N);
    hipLaunchKernelGGL(gemm1_k, dim3(gW), dim3(256), 0, stream, aggx, W1, b1, bufX, N);

    // layer 2: agg1 = A_norm h1, h2 = relu(agg1 @ W2 + b2)
    hipLaunchKernelGGL(agg512w_k, dim3(gW), dim3(256), 0, stream, bufX, bufY, offs, ssrc, sw, dis,
                       (const float*)nullptr, 0, N);
    hipLaunchKernelGGL(mfma_gemm_k, dim3(nby8 * 8), dim3(256), 0, stream,
                       bufY, w2t, b2, bufZ, N, 1024, 512, 1, 3);

    // layer 3: g3 = h2 @ W3, h3 = relu(A_norm g3 + b3)
    hipLaunchKernelGGL(mfma_gemm_k, dim3(nby8 * 4), dim3(256), 0, stream,
                       bufZ, w3t, (const float*)nullptr, bufX, N, 512, 1024, 0, 2);
    hipLaunchKernelGGL(agg512w_k, dim3(gW), dim3(256), 0, stream, bufX, bufY, offs, ssrc, sw, dis,
                       b3, 1, N);

    // mean pool (+counts) + head
    hipLaunchKernelGGL(pool_k, dim3(256), dim3(256), 0, stream, bufY, batch, gsum, gcnt, N);
    hipLaunchKernelGGL(fc_k, dim3(NGRAPH), dim3(128), 0, stream, gsum, gcnt, fcw1, fcb1, fcw2, fcb2, out);
}